// Round 3
// baseline (722.972 us; speedup 1.0000x reference)
//
#include <hip/hip_runtime.h>
#include <stdint.h>

#define B_ 8
#define S_ 2048
#define H_ 512
#define R_ 7
#define K_ 10
#define L_ 4
#define G_ 4096   // 8*H : 7 relation slices + self slice
#define RH_ 3584  // R*H

typedef __attribute__((ext_vector_type(8))) short bf16x8;
typedef __attribute__((ext_vector_type(4))) float f32x4;
typedef __attribute__((ext_vector_type(4))) unsigned short u16x4;
typedef unsigned long long u64;

__device__ __forceinline__ unsigned short f2bf(float f){
  unsigned int u = __float_as_uint(f);
  u = (u + 0x7fffu + ((u >> 16) & 1u)) >> 16;  // RNE
  return (unsigned short)u;
}

__device__ __forceinline__ float bf2f(unsigned short s){
  return __uint_as_float(((unsigned int)s) << 16);
}

__device__ __forceinline__ f32x4 bf4load(const unsigned short* p){
  u16x4 v = *(const u16x4*)p;
  f32x4 o;
#pragma unroll
  for (int e = 0; e < 4; e++) o[e] = bf2f(v[e]);
  return o;
}

__device__ __forceinline__ void gload16(const void* g, void* lds){
  __builtin_amdgcn_global_load_lds(
      (const __attribute__((address_space(1))) unsigned int*)g,
      (__attribute__((address_space(3))) unsigned int*)lds, 16, 0, 0);
}

// ---------------- KNN: per (b,i) find 10 nearest (excl self), exact f32 ops ---
__global__ __launch_bounds__(256) void knn_kernel(const float* __restrict__ pos,
                                                  int* __restrict__ knn){
  __shared__ float px[S_], py[S_], pz[S_];
  int b = blockIdx.y;
  const float* p = pos + (size_t)b * S_ * 3;
  for (int idx = threadIdx.x; idx < S_; idx += 256){
    px[idx] = p[idx*3+0]; py[idx] = p[idx*3+1]; pz[idx] = p[idx*3+2];
  }
  __syncthreads();
  int w = threadIdx.x >> 6, l = threadIdx.x & 63;
  int i = blockIdx.x * 4 + w;
  float xi = px[i], yi = py[i], zi = pz[i];
  u64 best[10];
#pragma unroll
  for (int q = 0; q < 10; q++) best[q] = ~0ull;
  for (int j = l; j < S_; j += 64){
    if (j == i) continue;
    float dx = __fsub_rn(xi, px[j]);
    float dy = __fsub_rn(yi, py[j]);
    float dz = __fsub_rn(zi, pz[j]);
    float d2 = __fadd_rn(__fadd_rn(__fmul_rn(dx,dx), __fmul_rn(dy,dy)), __fmul_rn(dz,dz));
    u64 key = ((u64)__float_as_uint(d2) << 32) | (unsigned)j;  // lex (d2, j)
    if (key < best[9]){
      best[9] = key;
#pragma unroll
      for (int q = 9; q > 0; --q){      // one bubble pass (rest sorted)
        u64 a = best[q-1], c = best[q];
        u64 lo = a < c ? a : c, hi = a < c ? c : a;
        best[q-1] = lo; best[q] = hi;
      }
    }
  }
  int* out = knn + ((size_t)b * S_ + i) * K_;
#pragma unroll
  for (int t = 0; t < 10; t++){
    u64 cand = best[0];
    u64 m = cand;
#pragma unroll
    for (int o = 32; o; o >>= 1){
      u64 other = __shfl_xor(m, o);
      if (other < m) m = other;
    }
    if (cand == m){
#pragma unroll
      for (int q = 0; q < 9; q++) best[q] = best[q+1];
      best[9] = ~0ull;
    }
    if (l == 0) out[t] = (int)(unsigned)(m & 0xffffffffu);
  }
}

// ---------------- CSR build (transpose KNN adjacency) -----------------------
__global__ void count_kernel(const int* __restrict__ knn, int* __restrict__ counts){
  int idx = blockIdx.x * 256 + threadIdx.x;     // B*S*K total
  int b = idx / (S_ * K_);
  int d = knn[idx];
  atomicAdd(&counts[b * S_ + d], 1);
}

__global__ __launch_bounds__(256) void scan_kernel(const int* __restrict__ counts,
                                                   int* __restrict__ row_start,
                                                   int* __restrict__ cursor){
  __shared__ int lds[256];
  int b = blockIdx.x, t = threadIdx.x;
  int base = b * S_;
  int v[8]; int s = 0;
#pragma unroll
  for (int e = 0; e < 8; e++){ v[e] = s; s += counts[base + t*8 + e]; }
  lds[t] = s;
  __syncthreads();
  int total = s;
  for (int o = 1; o < 256; o <<= 1){
    int add = 0;
    if (t >= o) add = lds[t - o];
    __syncthreads();
    lds[t] += add;
    __syncthreads();
  }
  int ex = lds[t] - total;
  int rb = b * (S_ + 1);
#pragma unroll
  for (int e = 0; e < 8; e++){
    int val = ex + v[e];
    row_start[rb + t*8 + e] = val;
    cursor[base + t*8 + e] = val;
  }
  if (t == 255) row_start[rb + S_] = lds[255];
}

__global__ void fill_kernel(const int* __restrict__ knn, int* __restrict__ cursor,
                            int* __restrict__ col){
  int idx = blockIdx.x * 256 + threadIdx.x;     // B*S*K
  int b = idx / (S_ * K_);
  int i = (idx / K_) % S_;
  int d = knn[idx];
  int p = atomicAdd(&cursor[b * S_ + d], 1);
  col[(size_t)b * S_ * K_ + p] = i;
}

__global__ void sort_kernel(const int* __restrict__ row_start, int* __restrict__ col){
  int idx = blockIdx.x * 256 + threadIdx.x;     // B*S
  int b = idx / S_, d = idx % S_;
  int rs = row_start[b*(S_+1)+d], re = row_start[b*(S_+1)+d+1];
  int* c = col + (size_t)b * S_ * K_;
  for (int a = rs + 1; a < re; ++a){
    int vv = c[a]; int q = a - 1;
    while (q >= rs && c[q] > vv){ c[q+1] = c[q]; --q; }
    c[q+1] = vv;
  }
}

// ---------------- weight prep: WcatT[l][m][k] bf16; folded BN affine --------
__global__ void prepw_kernel(const float* __restrict__ Wlin, const float* __restrict__ Wself,
                             unsigned short* __restrict__ Wt){
  int idx = blockIdx.x * 256 + threadIdx.x;     // L*4096*128
  int k = (idx & 127) * 4;
  int m = (idx >> 7) & 4095;
  int l = idx >> 19;
  const float* src;
  if (m < RH_){
    int r = m >> 9, j = m & 511;
    src = Wlin + ((size_t)l * H_ + j) * RH_ + r * 512 + k;
  } else {
    int j = m - RH_;
    src = Wself + ((size_t)l * H_ + j) * H_ + k;
  }
  unsigned int w0 = f2bf(src[0]) | ((unsigned)f2bf(src[1]) << 16);
  unsigned int w1 = f2bf(src[2]) | ((unsigned)f2bf(src[3]) << 16);
  uint2 u; u.x = w0; u.y = w1;
  *(uint2*)&Wt[((size_t)l * G_ + m) * H_ + k] = u;
}

__global__ void prepa_kernel(const float* __restrict__ gam, const float* __restrict__ bet,
                             const float* __restrict__ mean, const float* __restrict__ var,
                             const float* __restrict__ blin, const float* __restrict__ bself,
                             float* __restrict__ scale, float* __restrict__ shift){
  int idx = blockIdx.x * 256 + threadIdx.x;     // L*H
  float sc = gam[idx] * rsqrtf(var[idx] + 1e-5f);
  scale[idx] = sc;
  shift[idx] = bet[idx] + (blin[idx] + bself[idx] - mean[idx]) * sc;
}

// ---------------- h0 = pos @ Wp.T + bp --------------------------------------
__global__ void inith_kernel(const float* __restrict__ pos, const float* __restrict__ Wp,
                             const float* __restrict__ bp, float* __restrict__ h,
                             unsigned short* __restrict__ hb){
  int idx = blockIdx.x * 256 + threadIdx.x;     // B*S*(H/4)
  int j = (idx & 127) * 4;
  int bs = idx >> 7;
  const float* p = pos + (size_t)bs * 3;
  float x = p[0], y = p[1], z = p[2];
  f32x4 o;
#pragma unroll
  for (int e = 0; e < 4; e++){
    const float* wr = Wp + (j + e) * 3;
    o[e] = x * wr[0] + y * wr[1] + z * wr[2] + bp[j + e];
  }
  *(f32x4*)&h[(size_t)bs * H_ + j] = o;
  unsigned int w0 = f2bf(o[0]) | ((unsigned)f2bf(o[1]) << 16);
  unsigned int w1 = f2bf(o[2]) | ((unsigned)f2bf(o[3]) << 16);
  uint2 u; u.x = w0; u.y = w1;
  *(uint2*)&hb[(size_t)bs * H_ + j] = u;
}

// ---------------- GEMM: g[s,m] = sum_k hb[s,k] * Wt[m,k]  (bf16 MFMA) -------
// 256x256 tile, BK=32, 8 waves (2M x 4N, each 128x64 out), 3-slot LDS ring
// (96 KB), counted vmcnt(8) = 2 K-tiles in flight, raw barriers (no vmcnt(0)
// drain in steady loop), slot-XOR swizzled LDS, setprio around MFMA cluster,
// XCD-bijective block swizzle, bf16 output.
__global__ __launch_bounds__(512) void gemm_kernel(const unsigned short* __restrict__ A,
                                                   const unsigned short* __restrict__ Bw,
                                                   unsigned short* __restrict__ C){
  __shared__ unsigned short As[3][256 * 32];
  __shared__ unsigned short Bs[3][256 * 32];
  int tid = threadIdx.x;
  int nwg = gridDim.x;
  int q = nwg >> 3;
  int wg = blockIdx.x;
  int swz = (wg & 7) * q + (wg >> 3);
  int my = swz >> 4;          // M tile (16 N-tiles, x fastest)
  int nx = swz & 15;          // N tile
  int l = tid & 63, wid = tid >> 6;
  int wm = wid >> 2, wn = wid & 3;          // 2M x 4N waves
  size_t aBase = (size_t)my * 256;
  size_t bBase = (size_t)nx * 256;
  f32x4 acc[8][4] = {};

  // staging coords: thread handles chunks c = tid, tid+512 of the 256x32 tile
  int rowA0 = tid >> 2, rowA1 = (tid + 512) >> 2;
  int kc0 = (tid & 3) ^ ((rowA0 >> 1) & 3);
  int kc1 = (tid & 3) ^ ((rowA1 >> 1) & 3);
  const unsigned short* Ap0 = A  + (aBase + rowA0) * 512 + kc0 * 8;
  const unsigned short* Ap1 = A  + (aBase + rowA1) * 512 + kc1 * 8;
  const unsigned short* Bp0 = Bw + (bBase + rowA0) * 512 + kc0 * 8;
  const unsigned short* Bp1 = Bw + (bBase + rowA1) * 512 + kc1 * 8;
  int dst0 = tid * 8, dst1 = (tid + 512) * 8;

#define STAGE(sl, kt) do { int ko = (kt) * 32;             \
    gload16(Ap0 + ko, &As[sl][dst0]);                      \
    gload16(Ap1 + ko, &As[sl][dst1]);                      \
    gload16(Bp0 + ko, &Bs[sl][dst0]);                      \
    gload16(Bp1 + ko, &Bs[sl][dst1]);                      \
  } while (0)

  STAGE(0, 0);
  STAGE(1, 1);

  int kcr = l >> 4;      // k-chunk 0..3 for frag reads
  int lr = l & 15;
  int s = 0;
  for (int kt = 0; kt < 16; ++kt){
    int s2 = s + 2; if (s2 >= 3) s2 -= 3;
    if (kt < 14) STAGE(s2, kt + 2);
    // counted vmcnt: keep (kt+1, kt+2) tiles' 8 loads in flight; kt's landed
    if (kt < 14)       asm volatile("s_waitcnt vmcnt(8)" ::: "memory");
    else if (kt == 14) asm volatile("s_waitcnt vmcnt(4)" ::: "memory");
    else               asm volatile("s_waitcnt vmcnt(0)" ::: "memory");
    __builtin_amdgcn_s_barrier();
    asm volatile("" ::: "memory");

    const unsigned short* Abuf = As[s];
    const unsigned short* Bbuf = Bs[s];
    bf16x8 bfr[4], afr[8];
#pragma unroll
    for (int ni = 0; ni < 4; ni++){
      int row = wn * 64 + ni * 16 + lr;
      int slot = kcr ^ ((row >> 1) & 3);
      bfr[ni] = *(const bf16x8*)&Bbuf[row * 32 + slot * 8];
    }
#pragma unroll
    for (int mi = 0; mi < 8; mi++){
      int row = wm * 128 + mi * 16 + lr;
      int slot = kcr ^ ((row >> 1) & 3);
      afr[mi] = *(const bf16x8*)&Abuf[row * 32 + slot * 8];
    }
    __builtin_amdgcn_s_setprio(1);
#pragma unroll
    for (int mi = 0; mi < 8; mi++)
#pragma unroll
      for (int ni = 0; ni < 4; ni++)
        acc[mi][ni] = __builtin_amdgcn_mfma_f32_16x16x32_bf16(afr[mi], bfr[ni], acc[mi][ni], 0, 0, 0);
    __builtin_amdgcn_s_setprio(0);

    asm volatile("" ::: "memory");
    __builtin_amdgcn_s_barrier();     // all waves done reading slot s
    asm volatile("" ::: "memory");
    ++s; if (s == 3) s = 0;
  }
#undef STAGE

  int r0 = (l >> 4) * 4, cc0 = l & 15;
#pragma unroll
  for (int mi = 0; mi < 8; mi++)
#pragma unroll
    for (int ni = 0; ni < 4; ni++){
      size_t ccol = bBase + wn * 64 + ni * 16 + cc0;
#pragma unroll
      for (int reg = 0; reg < 4; reg++){
        size_t rrow = aBase + wm * 128 + mi * 16 + r0 + reg;
        C[rrow * G_ + ccol] = f2bf(acc[mi][ni][reg]);
      }
    }
}

// ---------------- combine: shifts + CSR gather + BN affine + relu + residual -
__global__ __launch_bounds__(128) void combine_kernel(
    const unsigned short* __restrict__ g, long long gStride,
    float* __restrict__ h, unsigned short* __restrict__ hb,
    const int* __restrict__ row_start, const int* __restrict__ col,
    const float* __restrict__ scale, const float* __restrict__ shift,
    int l, int b0){
  int bx = blockIdx.x;
  int d = (bx & 7) * 256 + (bx >> 3);     // XCD-contiguous d chunks
  int bg = blockIdx.y;
  int b = b0 + bg;
  const unsigned short* gg = g + (size_t)bg * (size_t)gStride;
  int j = threadIdx.x * 4;
  int rs = row_start[b * (S_ + 1) + d];
  int re = row_start[b * (S_ + 1) + d + 1];
  const int* cl = col + (size_t)b * S_ * K_;
  f32x4 acc = bf4load(&gg[(size_t)d * G_ + 7 * 512 + j]);   // self (Wself)
  const int offs[6] = {-3, -2, -1, 1, 2, 3};
#pragma unroll
  for (int r = 0; r < 6; r++){
    int src = d - offs[r];
    if ((unsigned)src < S_)
      acc += bf4load(&gg[(size_t)src * G_ + r * 512 + j]);
  }
  for (int e = rs; e < re; ++e){
    int i = cl[e];
    acc += bf4load(&gg[(size_t)i * G_ + 6 * 512 + j]);
  }
  f32x4 sc = *(const f32x4*)&scale[l * H_ + j];
  f32x4 sh = *(const f32x4*)&shift[l * H_ + j];
  f32x4 o = acc * sc + sh;
#pragma unroll
  for (int e = 0; e < 4; e++) o[e] = fmaxf(o[e], 0.f);
  size_t hoff = ((size_t)b * S_ + d) * H_ + j;
  f32x4 hv = *(const f32x4*)&h[hoff];
  hv += o;
  *(f32x4*)&h[hoff] = hv;
  unsigned int w0 = f2bf(hv[0]) | ((unsigned)f2bf(hv[1]) << 16);
  unsigned int w1 = f2bf(hv[2]) | ((unsigned)f2bf(hv[3]) << 16);
  uint2 u; u.x = w0; u.y = w1;
  *(uint2*)&hb[hoff] = u;
}

extern "C" void kernel_launch(void* const* d_in, const int* in_sizes, int n_in,
                              void* d_out, int out_size, void* d_ws, size_t ws_size,
                              hipStream_t stream){
  const float* ca    = (const float*)d_in[1];
  const float* Wp    = (const float*)d_in[3];
  const float* bp    = (const float*)d_in[4];
  const float* Wlin  = (const float*)d_in[5];
  const float* blin  = (const float*)d_in[6];
  const float* Wself = (const float*)d_in[7];
  const float* bself = (const float*)d_in[8];
  const float* gam   = (const float*)d_in[9];
  const float* bet   = (const float*)d_in[10];
  const float* mean  = (const float*)d_in[11];
  const float* var   = (const float*)d_in[12];
  float* h = (float*)d_out;

  char* ws = (char*)d_ws;
  size_t off = 0;
  auto alloc = [&](size_t bytes) -> char* {
    char* p = ws + off;
    off = (off + bytes + 255) & ~(size_t)255;
    return p;
  };
  int* knn       = (int*)alloc((size_t)B_ * S_ * K_ * 4);
  int* counts    = (int*)alloc((size_t)B_ * S_ * 4);
  int* row_start = (int*)alloc((size_t)B_ * (S_ + 1) * 4);
  int* cursor    = (int*)alloc((size_t)B_ * S_ * 4);
  int* col       = (int*)alloc((size_t)B_ * S_ * K_ * 4);
  unsigned short* Wt = (unsigned short*)alloc((size_t)L_ * G_ * H_ * 2);
  float* scale   = (float*)alloc((size_t)L_ * H_ * 4);
  float* shift   = (float*)alloc((size_t)L_ * H_ * 4);
  unsigned short* hb = (unsigned short*)alloc((size_t)B_ * S_ * H_ * 2);
  size_t fixed = off;
  size_t gFull = (size_t)B_ * S_ * G_ * 2;       // bf16 g
  size_t gOne  = (size_t)S_ * G_ * 2;
  bool batched = (fixed + gFull) <= ws_size;
  unsigned short* g = (unsigned short*)alloc(batched ? gFull : gOne);

  hipMemsetAsync(counts, 0, (size_t)B_ * S_ * 4, stream);
  knn_kernel<<<dim3(S_ / 4, B_), 256, 0, stream>>>(ca, knn);
  count_kernel<<<dim3(B_ * S_ * K_ / 256), 256, 0, stream>>>(knn, counts);
  scan_kernel<<<dim3(B_), 256, 0, stream>>>(counts, row_start, cursor);
  fill_kernel<<<dim3(B_ * S_ * K_ / 256), 256, 0, stream>>>(knn, cursor, col);
  sort_kernel<<<dim3(B_ * S_ / 256), 256, 0, stream>>>(row_start, col);
  prepw_kernel<<<dim3(L_ * G_ * (H_ / 4) / 256), 256, 0, stream>>>(Wlin, Wself, Wt);
  prepa_kernel<<<dim3(L_ * H_ / 256), 256, 0, stream>>>(gam, bet, mean, var, blin, bself, scale, shift);
  inith_kernel<<<dim3(B_ * S_ * (H_ / 4) / 256), 256, 0, stream>>>(ca, Wp, bp, h, hb);

  for (int l = 0; l < L_; l++){
    const unsigned short* Wtl = Wt + (size_t)l * G_ * H_;
    if (batched){
      gemm_kernel<<<dim3((B_ * S_ / 256) * 16), 512, 0, stream>>>(hb, Wtl, g);
      combine_kernel<<<dim3(S_, B_), 128, 0, stream>>>(g, (long long)S_ * G_, h, hb,
                                                       row_start, col, scale, shift, l, 0);
    } else {
      for (int b = 0; b < B_; b++){
        gemm_kernel<<<dim3((S_ / 256) * 16), 512, 0, stream>>>(hb + (size_t)b * S_ * H_, Wtl, g);
        combine_kernel<<<dim3(S_, 1), 128, 0, stream>>>(g, 0, h, hb,
                                                        row_start, col, scale, shift, l, b);
      }
    }
  }
}

// Round 4
// 668.781 us; speedup vs baseline: 1.0810x; 1.0810x over previous
//
#include <hip/hip_runtime.h>
#include <stdint.h>

#define B_ 8
#define S_ 2048
#define H_ 512
#define R_ 7
#define K_ 10
#define L_ 4
#define KT_ 4096  // fused K dim: 7 relation slices + self slice
#define RH_ 3584  // R*H

typedef __attribute__((ext_vector_type(8))) short bf16x8;
typedef __attribute__((ext_vector_type(4))) float f32x4;
typedef __attribute__((ext_vector_type(4))) unsigned short u16x4;
typedef unsigned long long u64;

__device__ __forceinline__ unsigned short f2bf(float f){
  unsigned int u = __float_as_uint(f);
  u = (u + 0x7fffu + ((u >> 16) & 1u)) >> 16;  // RNE
  return (unsigned short)u;
}

__device__ __forceinline__ float bf2f(unsigned short s){
  return __uint_as_float(((unsigned int)s) << 16);
}

__device__ __forceinline__ f32x4 bf4load(const unsigned short* p){
  u16x4 v = *(const u16x4*)p;
  f32x4 o;
#pragma unroll
  for (int e = 0; e < 4; e++) o[e] = bf2f(v[e]);
  return o;
}

__device__ __forceinline__ void gload16(const void* g, void* lds){
  __builtin_amdgcn_global_load_lds(
      (const __attribute__((address_space(1))) unsigned int*)g,
      (__attribute__((address_space(3))) unsigned int*)lds, 16, 0, 0);
}

// ---------------- KNN: per (b,i) find 10 nearest (excl self), exact f32 ops ---
__global__ __launch_bounds__(256) void knn_kernel(const float* __restrict__ pos,
                                                  int* __restrict__ knn){
  __shared__ float px[S_], py[S_], pz[S_];
  int b = blockIdx.y;
  const float* p = pos + (size_t)b * S_ * 3;
  for (int idx = threadIdx.x; idx < S_; idx += 256){
    px[idx] = p[idx*3+0]; py[idx] = p[idx*3+1]; pz[idx] = p[idx*3+2];
  }
  __syncthreads();
  int w = threadIdx.x >> 6, l = threadIdx.x & 63;
  int i = blockIdx.x * 4 + w;
  float xi = px[i], yi = py[i], zi = pz[i];
  u64 best[10];
#pragma unroll
  for (int q = 0; q < 10; q++) best[q] = ~0ull;
  for (int j = l; j < S_; j += 64){
    if (j == i) continue;
    float dx = __fsub_rn(xi, px[j]);
    float dy = __fsub_rn(yi, py[j]);
    float dz = __fsub_rn(zi, pz[j]);
    float d2 = __fadd_rn(__fadd_rn(__fmul_rn(dx,dx), __fmul_rn(dy,dy)), __fmul_rn(dz,dz));
    u64 key = ((u64)__float_as_uint(d2) << 32) | (unsigned)j;  // lex (d2, j)
    if (key < best[9]){
      best[9] = key;
#pragma unroll
      for (int q = 9; q > 0; --q){      // one bubble pass (rest sorted)
        u64 a = best[q-1], c = best[q];
        u64 lo = a < c ? a : c, hi = a < c ? c : a;
        best[q-1] = lo; best[q] = hi;
      }
    }
  }
  int* out = knn + ((size_t)b * S_ + i) * K_;
#pragma unroll
  for (int t = 0; t < 10; t++){
    u64 cand = best[0];
    u64 m = cand;
#pragma unroll
    for (int o = 32; o; o >>= 1){
      u64 other = __shfl_xor(m, o);
      if (other < m) m = other;
    }
    if (cand == m){
#pragma unroll
      for (int q = 0; q < 9; q++) best[q] = best[q+1];
      best[9] = ~0ull;
    }
    if (l == 0) out[t] = (int)(unsigned)(m & 0xffffffffu);
  }
}

// ---------------- CSR build (transpose KNN adjacency) -----------------------
__global__ void count_kernel(const int* __restrict__ knn, int* __restrict__ counts){
  int idx = blockIdx.x * 256 + threadIdx.x;     // B*S*K total
  int b = idx / (S_ * K_);
  int d = knn[idx];
  atomicAdd(&counts[b * S_ + d], 1);
}

__global__ __launch_bounds__(256) void scan_kernel(const int* __restrict__ counts,
                                                   int* __restrict__ row_start,
                                                   int* __restrict__ cursor){
  __shared__ int lds[256];
  int b = blockIdx.x, t = threadIdx.x;
  int base = b * S_;
  int v[8]; int s = 0;
#pragma unroll
  for (int e = 0; e < 8; e++){ v[e] = s; s += counts[base + t*8 + e]; }
  lds[t] = s;
  __syncthreads();
  int total = s;
  for (int o = 1; o < 256; o <<= 1){
    int add = 0;
    if (t >= o) add = lds[t - o];
    __syncthreads();
    lds[t] += add;
    __syncthreads();
  }
  int ex = lds[t] - total;
  int rb = b * (S_ + 1);
#pragma unroll
  for (int e = 0; e < 8; e++){
    int val = ex + v[e];
    row_start[rb + t*8 + e] = val;
    cursor[base + t*8 + e] = val;
  }
  if (t == 255) row_start[rb + S_] = lds[255];
}

__global__ void fill_kernel(const int* __restrict__ knn, int* __restrict__ cursor,
                            int* __restrict__ col){
  int idx = blockIdx.x * 256 + threadIdx.x;     // B*S*K
  int b = idx / (S_ * K_);
  int i = (idx / K_) % S_;
  int d = knn[idx];
  int p = atomicAdd(&cursor[b * S_ + d], 1);
  col[(size_t)b * S_ * K_ + p] = i;
}

__global__ void sort_kernel(const int* __restrict__ row_start, int* __restrict__ col){
  int idx = blockIdx.x * 256 + threadIdx.x;     // B*S
  int b = idx / S_, d = idx % S_;
  int rs = row_start[b*(S_+1)+d], re = row_start[b*(S_+1)+d+1];
  int* c = col + (size_t)b * S_ * K_;
  for (int a = rs + 1; a < re; ++a){
    int vv = c[a]; int q = a - 1;
    while (q >= rs && c[q] > vv){ c[q+1] = c[q]; --q; }
    c[q+1] = vv;
  }
}

// ---------------- weight prep: Wt[l][j=512][k=4096] = [Wlin[l][j] | Wself[l][j]]
__global__ void prepw_kernel(const float* __restrict__ Wlin, const float* __restrict__ Wself,
                             unsigned short* __restrict__ Wt){
  size_t e = ((size_t)blockIdx.x * 256 + threadIdx.x) * 8;   // L*512*4096 elements
  int k = (int)(e & 4095);
  int j = (int)((e >> 12) & 511);
  int l = (int)(e >> 21);
  const float* src = (k < RH_) ? Wlin + ((size_t)l * H_ + j) * RH_ + k
                               : Wself + ((size_t)l * H_ + j) * H_ + (k - RH_);
  union { unsigned short s[8]; uint4 u; } pk;
#pragma unroll
  for (int t = 0; t < 8; t++) pk.s[t] = f2bf(src[t]);
  *(uint4*)&Wt[e] = pk.u;
}

__global__ void prepa_kernel(const float* __restrict__ gam, const float* __restrict__ bet,
                             const float* __restrict__ mean, const float* __restrict__ var,
                             const float* __restrict__ blin, const float* __restrict__ bself,
                             float* __restrict__ scale, float* __restrict__ shift){
  int idx = blockIdx.x * 256 + threadIdx.x;     // L*H
  float sc = gam[idx] * rsqrtf(var[idx] + 1e-5f);
  scale[idx] = sc;
  shift[idx] = bet[idx] + (blin[idx] + bself[idx] - mean[idx]) * sc;
}

// ---------------- h0 = pos @ Wp.T + bp --------------------------------------
__global__ void inith_kernel(const float* __restrict__ pos, const float* __restrict__ Wp,
                             const float* __restrict__ bp, float* __restrict__ h,
                             unsigned short* __restrict__ hb){
  int idx = blockIdx.x * 256 + threadIdx.x;     // B*S*(H/4)
  int j = (idx & 127) * 4;
  int bs = idx >> 7;
  const float* p = pos + (size_t)bs * 3;
  float x = p[0], y = p[1], z = p[2];
  f32x4 o;
#pragma unroll
  for (int e = 0; e < 4; e++){
    const float* wr = Wp + (j + e) * 3;
    o[e] = x * wr[0] + y * wr[1] + z * wr[2] + bp[j + e];
  }
  *(f32x4*)&h[(size_t)bs * H_ + j] = o;
  unsigned int w0 = f2bf(o[0]) | ((unsigned)f2bf(o[1]) << 16);
  unsigned int w1 = f2bf(o[2]) | ((unsigned)f2bf(o[3]) << 16);
  uint2 u; u.x = w0; u.y = w1;
  *(uint2*)&hb[(size_t)bs * H_ + j] = u;
}

// ---------------- hknn[d] = sum_{i: d in knn(i)} hb[i]  (bf16 out) ----------
__global__ __launch_bounds__(128) void hknn_kernel(const unsigned short* __restrict__ hb,
                                                   const int* __restrict__ row_start,
                                                   const int* __restrict__ col,
                                                   unsigned short* __restrict__ hk){
  int bx = blockIdx.x;
  int d = (bx & 7) * 256 + (bx >> 3);     // XCD-contiguous d chunks
  int b = blockIdx.y;
  int j = threadIdx.x * 4;
  int rs = row_start[b * (S_ + 1) + d];
  int re = row_start[b * (S_ + 1) + d + 1];
  const int* cl = col + (size_t)b * S_ * K_;
  f32x4 acc = {0.f, 0.f, 0.f, 0.f};
  for (int e = rs; e < re; ++e){
    int i = cl[e];
    acc += bf4load(&hb[((size_t)b * S_ + i) * H_ + j]);
  }
  u16x4 v;
#pragma unroll
  for (int e = 0; e < 4; e++) v[e] = f2bf(acc[e]);
  *(u16x4*)&hk[((size_t)b * S_ + d) * H_ + j] = v;
}

// ---------------- fused GEMM: out = [shifted-h slices | hknn | h] @ Wt.T ----
// M=16384, N=512, K=4096. 128x128 tile, BK=32, 4 waves (2x2 of 64x64),
// global_load_lds 16B with per-lane shifted global source (zero-page redirect
// for invalid rows), slot-XOR swizzled LDS, 2-phase double-buffer.
// Epilogue: BN affine + relu + residual -> h (f32) and hbout (bf16).
__global__ __launch_bounds__(256) void gemmf_kernel(
    const unsigned short* __restrict__ hbin,
    const unsigned short* __restrict__ hkn,
    const unsigned short* __restrict__ Wt,     // [512][4096] this layer
    float* __restrict__ h,
    unsigned short* __restrict__ hbout,
    const float* __restrict__ scale,           // [512] this layer
    const float* __restrict__ shift,
    const unsigned short* __restrict__ zbuf){
  __shared__ unsigned short At[2][128 * 32];
  __shared__ unsigned short Bt[2][128 * 32];
  int tid = threadIdx.x;
  int nwg = gridDim.x;          // 512
  int q = nwg >> 3;
  int wg = blockIdx.x;
  int swz = (wg & 7) * q + (wg >> 3);
  int my = swz >> 2;            // 128 M tiles (4 N tiles, x fastest)
  int nx = swz & 3;
  int l = tid & 63, w = tid >> 6;
  int wrow = (w >> 1) * 64, wcol = (w & 1) * 64;
  int aBase = my * 128;
  int bBase = nx * 128;
  f32x4 acc[4][4] = {};

  int row0 = tid >> 2;                         // tile-local rows row0, row0+64
  int kc = (tid & 3) ^ ((row0 >> 1) & 3);      // slot-XOR swizzle
  int gr0 = aBase + row0, gr1 = gr0 + 64;
  const unsigned short* Bp0 = Wt + (size_t)(bBase + row0) * KT_ + kc * 8;
  const unsigned short* Bp1 = Wt + (size_t)(bBase + row0 + 64) * KT_ + kc * 8;
  int dst0 = tid * 8, dst1 = (tid + 256) * 8;

  int kcr = l >> 4, lr = l & 15;
  int cur = 0;

  for (int r = 0; r < 8; ++r){
    // per-slice A source pointers (per-lane shifted rows; invalid -> zbuf)
    const unsigned short *a0, *a1;
    if (r < 6){
      int sh_ = (r < 3) ? (3 - r) : (2 - r);   // src = d - off_r
      int s0 = gr0 + sh_, s1 = gr1 + sh_;
      a0 = (((unsigned)s0 >> 11) == ((unsigned)gr0 >> 11)) ? hbin + (size_t)s0 * H_ : zbuf;
      a1 = (((unsigned)s1 >> 11) == ((unsigned)gr1 >> 11)) ? hbin + (size_t)s1 * H_ : zbuf;
    } else {
      const unsigned short* base = (r == 6) ? hkn : hbin;
      a0 = base + (size_t)gr0 * H_;
      a1 = base + (size_t)gr1 * H_;
    }
    a0 += kc * 8; a1 += kc * 8;
    const unsigned short* b0 = Bp0 + r * 512;
    const unsigned short* b1 = Bp1 + r * 512;

    // stage ks=0 of this slice
    gload16(a0, &At[cur][dst0]); gload16(a1, &At[cur][dst1]);
    gload16(b0, &Bt[cur][dst0]); gload16(b1, &Bt[cur][dst1]);
    __syncthreads();

    for (int ks = 0; ks < 16; ++ks){
      if (ks < 15){
        int ko = (ks + 1) * 32;
        gload16(a0 + ko, &At[cur ^ 1][dst0]); gload16(a1 + ko, &At[cur ^ 1][dst1]);
        gload16(b0 + ko, &Bt[cur ^ 1][dst0]); gload16(b1 + ko, &Bt[cur ^ 1][dst1]);
      }
      bf16x8 af[4], bf[4];
#pragma unroll
      for (int mi = 0; mi < 4; mi++){
        int row = wrow + mi * 16 + lr;
        int slot = kcr ^ ((row >> 1) & 3);
        af[mi] = *(const bf16x8*)&At[cur][row * 32 + slot * 8];
      }
#pragma unroll
      for (int ni = 0; ni < 4; ni++){
        int row = wcol + ni * 16 + lr;
        int slot = kcr ^ ((row >> 1) & 3);
        bf[ni] = *(const bf16x8*)&Bt[cur][row * 32 + slot * 8];
      }
#pragma unroll
      for (int mi = 0; mi < 4; mi++)
#pragma unroll
        for (int ni = 0; ni < 4; ni++)
          acc[mi][ni] = __builtin_amdgcn_mfma_f32_16x16x32_bf16(af[mi], bf[ni], acc[mi][ni], 0, 0, 0);
      __syncthreads();
      cur ^= 1;
    }
  }

  // epilogue: BN affine + relu + residual
  int r0 = (l >> 4) * 4, c0 = l & 15;
#pragma unroll
  for (int ni = 0; ni < 4; ni++){
    int gcol = bBase + wcol + ni * 16 + c0;
    float sc = scale[gcol], sf = shift[gcol];
#pragma unroll
    for (int mi = 0; mi < 4; mi++){
#pragma unroll
      for (int reg = 0; reg < 4; reg++){
        int grow = aBase + wrow + mi * 16 + r0 + reg;
        size_t o = (size_t)grow * H_ + gcol;
        float val = fmaxf(acc[mi][ni][reg] * sc + sf, 0.f);
        float hv = h[o] + val;
        h[o] = hv;
        hbout[o] = f2bf(hv);
      }
    }
  }
}

extern "C" void kernel_launch(void* const* d_in, const int* in_sizes, int n_in,
                              void* d_out, int out_size, void* d_ws, size_t ws_size,
                              hipStream_t stream){
  const float* ca    = (const float*)d_in[1];
  const float* Wp    = (const float*)d_in[3];
  const float* bp    = (const float*)d_in[4];
  const float* Wlin  = (const float*)d_in[5];
  const float* blin  = (const float*)d_in[6];
  const float* Wself = (const float*)d_in[7];
  const float* bself = (const float*)d_in[8];
  const float* gam   = (const float*)d_in[9];
  const float* bet   = (const float*)d_in[10];
  const float* mean  = (const float*)d_in[11];
  const float* var   = (const float*)d_in[12];
  float* h = (float*)d_out;

  char* ws = (char*)d_ws;
  size_t off = 0;
  auto alloc = [&](size_t bytes) -> char* {
    char* p = ws + off;
    off = (off + bytes + 255) & ~(size_t)255;
    return p;
  };
  int* knn       = (int*)alloc((size_t)B_ * S_ * K_ * 4);
  int* counts    = (int*)alloc((size_t)B_ * S_ * 4);
  int* row_start = (int*)alloc((size_t)B_ * (S_ + 1) * 4);
  int* cursor    = (int*)alloc((size_t)B_ * S_ * 4);
  int* col       = (int*)alloc((size_t)B_ * S_ * K_ * 4);
  unsigned short* Wt  = (unsigned short*)alloc((size_t)L_ * H_ * KT_ * 2);
  float* scale   = (float*)alloc((size_t)L_ * H_ * 4);
  float* shift   = (float*)alloc((size_t)L_ * H_ * 4);
  unsigned short* hbA = (unsigned short*)alloc((size_t)B_ * S_ * H_ * 2);
  unsigned short* hbB = (unsigned short*)alloc((size_t)B_ * S_ * H_ * 2);
  unsigned short* hkn = (unsigned short*)alloc((size_t)B_ * S_ * H_ * 2);
  unsigned short* zbuf = (unsigned short*)alloc(4096 * 2);

  hipMemsetAsync(counts, 0, (size_t)B_ * S_ * 4, stream);
  hipMemsetAsync(zbuf, 0, 4096 * 2, stream);
  knn_kernel<<<dim3(S_ / 4, B_), 256, 0, stream>>>(ca, knn);
  count_kernel<<<dim3(B_ * S_ * K_ / 256), 256, 0, stream>>>(knn, counts);
  scan_kernel<<<dim3(B_), 256, 0, stream>>>(counts, row_start, cursor);
  fill_kernel<<<dim3(B_ * S_ * K_ / 256), 256, 0, stream>>>(knn, cursor, col);
  sort_kernel<<<dim3(B_ * S_ / 256), 256, 0, stream>>>(row_start, col);
  prepw_kernel<<<dim3((int)((size_t)L_ * H_ * KT_ / 8 / 256)), 256, 0, stream>>>(Wlin, Wself, Wt);
  prepa_kernel<<<dim3(L_ * H_ / 256), 256, 0, stream>>>(gam, bet, mean, var, blin, bself, scale, shift);
  inith_kernel<<<dim3(B_ * S_ * (H_ / 4) / 256), 256, 0, stream>>>(ca, Wp, bp, h, hbA);

  for (int l = 0; l < L_; l++){
    unsigned short* in  = (l & 1) ? hbB : hbA;
    unsigned short* out = (l & 1) ? hbA : hbB;
    hknn_kernel<<<dim3(S_, B_), 128, 0, stream>>>(in, row_start, col, hkn);
    gemmf_kernel<<<dim3((B_ * S_ / 128) * 4), 256, 0, stream>>>(
        in, hkn, Wt + (size_t)l * H_ * KT_, h, out,
        scale + l * H_, shift + l * H_, zbuf);
  }
}

// Round 5
// 600.706 us; speedup vs baseline: 1.2035x; 1.1133x over previous
//
#include <hip/hip_runtime.h>
#include <stdint.h>

#define B_ 8
#define S_ 2048
#define H_ 512
#define R_ 7
#define K_ 10
#define L_ 4
#define KT_ 4096  // fused K dim: 7 relation slices + self slice
#define RH_ 3584  // R*H

typedef __attribute__((ext_vector_type(8))) short bf16x8;
typedef __attribute__((ext_vector_type(4))) float f32x4;
typedef __attribute__((ext_vector_type(4))) unsigned short u16x4;
typedef unsigned long long u64;

__device__ __forceinline__ unsigned short f2bf(float f){
  unsigned int u = __float_as_uint(f);
  u = (u + 0x7fffu + ((u >> 16) & 1u)) >> 16;  // RNE
  return (unsigned short)u;
}

__device__ __forceinline__ float bf2f(unsigned short s){
  return __uint_as_float(((unsigned int)s) << 16);
}

__device__ __forceinline__ f32x4 bf4load(const unsigned short* p){
  u16x4 v = *(const u16x4*)p;
  f32x4 o;
#pragma unroll
  for (int e = 0; e < 4; e++) o[e] = bf2f(v[e]);
  return o;
}

__device__ __forceinline__ void gload16(const void* g, void* lds){
  __builtin_amdgcn_global_load_lds(
      (const __attribute__((address_space(1))) unsigned int*)g,
      (__attribute__((address_space(3))) unsigned int*)lds, 16, 0, 0);
}

// ---------------- KNN: per (b,i) find 10 nearest (excl self), exact f32 ops ---
__global__ __launch_bounds__(256) void knn_kernel(const float* __restrict__ pos,
                                                  int* __restrict__ knn){
  __shared__ float px[S_], py[S_], pz[S_];
  int b = blockIdx.y;
  const float* p = pos + (size_t)b * S_ * 3;
  for (int idx = threadIdx.x; idx < S_; idx += 256){
    px[idx] = p[idx*3+0]; py[idx] = p[idx*3+1]; pz[idx] = p[idx*3+2];
  }
  __syncthreads();
  int w = threadIdx.x >> 6, l = threadIdx.x & 63;
  int i = blockIdx.x * 4 + w;
  float xi = px[i], yi = py[i], zi = pz[i];
  u64 best[10];
#pragma unroll
  for (int q = 0; q < 10; q++) best[q] = ~0ull;
  for (int j = l; j < S_; j += 64){
    if (j == i) continue;
    float dx = __fsub_rn(xi, px[j]);
    float dy = __fsub_rn(yi, py[j]);
    float dz = __fsub_rn(zi, pz[j]);
    float d2 = __fadd_rn(__fadd_rn(__fmul_rn(dx,dx), __fmul_rn(dy,dy)), __fmul_rn(dz,dz));
    u64 key = ((u64)__float_as_uint(d2) << 32) | (unsigned)j;  // lex (d2, j)
    if (key < best[9]){
      best[9] = key;
#pragma unroll
      for (int q = 9; q > 0; --q){      // one bubble pass (rest sorted)
        u64 a = best[q-1], c = best[q];
        u64 lo = a < c ? a : c, hi = a < c ? c : a;
        best[q-1] = lo; best[q] = hi;
      }
    }
  }
  int* out = knn + ((size_t)b * S_ + i) * K_;
#pragma unroll
  for (int t = 0; t < 10; t++){
    u64 cand = best[0];
    u64 m = cand;
#pragma unroll
    for (int o = 32; o; o >>= 1){
      u64 other = __shfl_xor(m, o);
      if (other < m) m = other;
    }
    if (cand == m){
#pragma unroll
      for (int q = 0; q < 9; q++) best[q] = best[q+1];
      best[9] = ~0ull;
    }
    if (l == 0) out[t] = (int)(unsigned)(m & 0xffffffffu);
  }
}

// ---------------- CSR build (transpose KNN adjacency) -----------------------
__global__ void count_kernel(const int* __restrict__ knn, int* __restrict__ counts){
  int idx = blockIdx.x * 256 + threadIdx.x;     // B*S*K total
  int b = idx / (S_ * K_);
  int d = knn[idx];
  atomicAdd(&counts[b * S_ + d], 1);
}

__global__ __launch_bounds__(256) void scan_kernel(const int* __restrict__ counts,
                                                   int* __restrict__ row_start,
                                                   int* __restrict__ cursor){
  __shared__ int lds[256];
  int b = blockIdx.x, t = threadIdx.x;
  int base = b * S_;
  int v[8]; int s = 0;
#pragma unroll
  for (int e = 0; e < 8; e++){ v[e] = s; s += counts[base + t*8 + e]; }
  lds[t] = s;
  __syncthreads();
  int total = s;
  for (int o = 1; o < 256; o <<= 1){
    int add = 0;
    if (t >= o) add = lds[t - o];
    __syncthreads();
    lds[t] += add;
    __syncthreads();
  }
  int ex = lds[t] - total;
  int rb = b * (S_ + 1);
#pragma unroll
  for (int e = 0; e < 8; e++){
    int val = ex + v[e];
    row_start[rb + t*8 + e] = val;
    cursor[base + t*8 + e] = val;
  }
  if (t == 255) row_start[rb + S_] = lds[255];
}

__global__ void fill_kernel(const int* __restrict__ knn, int* __restrict__ cursor,
                            int* __restrict__ col){
  int idx = blockIdx.x * 256 + threadIdx.x;     // B*S*K
  int b = idx / (S_ * K_);
  int i = (idx / K_) % S_;
  int d = knn[idx];
  int p = atomicAdd(&cursor[b * S_ + d], 1);
  col[(size_t)b * S_ * K_ + p] = i;
}

__global__ void sort_kernel(const int* __restrict__ row_start, int* __restrict__ col){
  int idx = blockIdx.x * 256 + threadIdx.x;     // B*S
  int b = idx / S_, d = idx % S_;
  int rs = row_start[b*(S_+1)+d], re = row_start[b*(S_+1)+d+1];
  int* c = col + (size_t)b * S_ * K_;
  for (int a = rs + 1; a < re; ++a){
    int vv = c[a]; int q = a - 1;
    while (q >= rs && c[q] > vv){ c[q+1] = c[q]; --q; }
    c[q+1] = vv;
  }
}

// ---------------- weight prep: Wt[l][j=512][k=4096] = [Wlin[l][j] | Wself[l][j]]
__global__ void prepw_kernel(const float* __restrict__ Wlin, const float* __restrict__ Wself,
                             unsigned short* __restrict__ Wt){
  size_t e = ((size_t)blockIdx.x * 256 + threadIdx.x) * 8;   // L*512*4096 elements
  int k = (int)(e & 4095);
  int j = (int)((e >> 12) & 511);
  int l = (int)(e >> 21);
  const float* src = (k < RH_) ? Wlin + ((size_t)l * H_ + j) * RH_ + k
                               : Wself + ((size_t)l * H_ + j) * H_ + (k - RH_);
  union { unsigned short s[8]; uint4 u; } pk;
#pragma unroll
  for (int t = 0; t < 8; t++) pk.s[t] = f2bf(src[t]);
  *(uint4*)&Wt[e] = pk.u;
}

__global__ void prepa_kernel(const float* __restrict__ gam, const float* __restrict__ bet,
                             const float* __restrict__ mean, const float* __restrict__ var,
                             const float* __restrict__ blin, const float* __restrict__ bself,
                             float* __restrict__ scale, float* __restrict__ shift){
  int idx = blockIdx.x * 256 + threadIdx.x;     // L*H
  float sc = gam[idx] * rsqrtf(var[idx] + 1e-5f);
  scale[idx] = sc;
  shift[idx] = bet[idx] + (blin[idx] + bself[idx] - mean[idx]) * sc;
}

// ---------------- h0 = pos @ Wp.T + bp --------------------------------------
__global__ void inith_kernel(const float* __restrict__ pos, const float* __restrict__ Wp,
                             const float* __restrict__ bp, float* __restrict__ h,
                             unsigned short* __restrict__ hb){
  int idx = blockIdx.x * 256 + threadIdx.x;     // B*S*(H/4)
  int j = (idx & 127) * 4;
  int bs = idx >> 7;
  const float* p = pos + (size_t)bs * 3;
  float x = p[0], y = p[1], z = p[2];
  f32x4 o;
#pragma unroll
  for (int e = 0; e < 4; e++){
    const float* wr = Wp + (j + e) * 3;
    o[e] = x * wr[0] + y * wr[1] + z * wr[2] + bp[j + e];
  }
  *(f32x4*)&h[(size_t)bs * H_ + j] = o;
  unsigned int w0 = f2bf(o[0]) | ((unsigned)f2bf(o[1]) << 16);
  unsigned int w1 = f2bf(o[2]) | ((unsigned)f2bf(o[3]) << 16);
  uint2 u; u.x = w0; u.y = w1;
  *(uint2*)&hb[(size_t)bs * H_ + j] = u;
}

// ---------------- hknn[d] = sum_{i: d in knn(i)} hb[i]  (bf16 out) ----------
__global__ __launch_bounds__(128) void hknn_kernel(const unsigned short* __restrict__ hb,
                                                   const int* __restrict__ row_start,
                                                   const int* __restrict__ col,
                                                   unsigned short* __restrict__ hk){
  int bx = blockIdx.x;
  int d = (bx & 7) * 256 + (bx >> 3);     // XCD-contiguous d chunks
  int b = blockIdx.y;
  int j = threadIdx.x * 4;
  int rs = row_start[b * (S_ + 1) + d];
  int re = row_start[b * (S_ + 1) + d + 1];
  const int* cl = col + (size_t)b * S_ * K_;
  f32x4 acc = {0.f, 0.f, 0.f, 0.f};
  for (int e = rs; e < re; ++e){
    int i = cl[e];
    acc += bf4load(&hb[((size_t)b * S_ + i) * H_ + j]);
  }
  u16x4 v;
#pragma unroll
  for (int e = 0; e < 4; e++) v[e] = f2bf(acc[e]);
  *(u16x4*)&hk[((size_t)b * S_ + d) * H_ + j] = v;
}

// ---------------- fused GEMM: out = [shifted-h slices | hknn | h] @ Wt.T ----
// M=16384, N=512, K=4096. 128x128 tile, BK=32, 4 waves (2x2 of 64x64).
// 4-slot LDS ring (64 KB), prefetch depth 3, counted s_waitcnt vmcnt(12)
// (never 0 in steady state), raw s_barriers, setprio around MFMA cluster,
// slot-XOR swizzled LDS, per-lane shifted global source (zero-page redirect),
// XCD-bijective block swizzle.
// Epilogue: BN affine + relu + residual -> h (f32) and hbout (bf16).
__global__ __launch_bounds__(256) void gemmf_kernel(
    const unsigned short* __restrict__ hbin,
    const unsigned short* __restrict__ hkn,
    const unsigned short* __restrict__ Wt,     // [512][4096] this layer
    float* __restrict__ h,
    unsigned short* __restrict__ hbout,
    const float* __restrict__ scale,           // [512] this layer
    const float* __restrict__ shift,
    const unsigned short* __restrict__ zbuf){
  __shared__ unsigned short As[4][128 * 32];
  __shared__ unsigned short Bs[4][128 * 32];
  int tid = threadIdx.x;
  int nwg = gridDim.x;          // 512
  int q = nwg >> 3;
  int wg = blockIdx.x;
  int swz = (wg & 7) * q + (wg >> 3);
  int my = swz >> 2;            // 128 M tiles (4 N tiles, x fastest)
  int nx = swz & 3;
  int l = tid & 63, w = tid >> 6;
  int wrow = (w >> 1) * 64, wcol = (w & 1) * 64;
  int aBase = my * 128;
  int bBase = nx * 128;
  f32x4 acc[4][4] = {};

  int row0 = tid >> 2;                         // tile-local rows row0, row0+64
  int kc = (tid & 3) ^ ((row0 >> 1) & 3);      // slot-XOR swizzle
  int gr0 = aBase + row0, gr1 = gr0 + 64;
  const unsigned short* Bb0 = Wt + (size_t)(bBase + row0) * KT_ + kc * 8;
  const unsigned short* Bb1 = Wt + (size_t)(bBase + row0 + 64) * KT_ + kc * 8;
  int dst0 = tid * 8, dst1 = (tid + 256) * 8;

  // stage-cursor slice pointers (stage leads compute by 3 K-steps)
  const unsigned short *sa0, *sa1, *sb0, *sb1;

#define SETSLICE(rs) do {                                                     \
    int _r = (rs);                                                            \
    const unsigned short *_a0, *_a1;                                          \
    if (_r < 6){                                                              \
      int _sh = (_r < 3) ? (3 - _r) : (2 - _r);   /* src = d - off_r */       \
      int _s0 = gr0 + _sh, _s1 = gr1 + _sh;                                   \
      _a0 = (((unsigned)_s0 >> 11) == ((unsigned)gr0 >> 11)) ? hbin + (size_t)_s0 * H_ : zbuf; \
      _a1 = (((unsigned)_s1 >> 11) == ((unsigned)gr1 >> 11)) ? hbin + (size_t)_s1 * H_ : zbuf; \
    } else {                                                                  \
      const unsigned short* _bs = (_r == 6) ? hkn : hbin;                     \
      _a0 = _bs + (size_t)gr0 * H_; _a1 = _bs + (size_t)gr1 * H_;             \
    }                                                                         \
    sa0 = _a0 + kc * 8; sa1 = _a1 + kc * 8;                                   \
    sb0 = Bb0 + _r * 512; sb1 = Bb1 + _r * 512;                               \
  } while (0)

#define STAGE(sl, ksl) do { int _ko = (ksl) * 32;          \
    gload16(sa0 + _ko, &As[sl][dst0]);                     \
    gload16(sa1 + _ko, &As[sl][dst1]);                     \
    gload16(sb0 + _ko, &Bs[sl][dst0]);                     \
    gload16(sb1 + _ko, &Bs[sl][dst1]);                     \
  } while (0)

  SETSLICE(0);
  STAGE(0, 0); STAGE(1, 1); STAGE(2, 2);

  int kcr = l >> 4, lr = l & 15;
  int s = 0;
  for (int r = 0; r < 8; ++r){
#pragma unroll
    for (int ks = 0; ks < 16; ++ks){
      int s3 = s + 3; if (s3 >= 4) s3 -= 4;
      // stage K-step t+3 (t = r*16+ks) into slot s3
      if (r < 7 || ks < 13){
        if (ks == 13) SETSLICE(r + 1);
        STAGE(s3, (ks + 3) & 15);
      }
      // counted vmcnt: oldest 4 loads (this slot) landed; up to 12 in flight
      if (r < 7 || ks < 13)  asm volatile("s_waitcnt vmcnt(12)" ::: "memory");
      else if (ks == 13)     asm volatile("s_waitcnt vmcnt(8)" ::: "memory");
      else if (ks == 14)     asm volatile("s_waitcnt vmcnt(4)" ::: "memory");
      else                   asm volatile("s_waitcnt vmcnt(0)" ::: "memory");
      __builtin_amdgcn_s_barrier();
      asm volatile("" ::: "memory");

      const unsigned short* Abuf = As[s];
      const unsigned short* Bbuf = Bs[s];
      bf16x8 af[4], bf[4];
#pragma unroll
      for (int mi = 0; mi < 4; mi++){
        int row = wrow + mi * 16 + lr;
        int slot = kcr ^ ((row >> 1) & 3);
        af[mi] = *(const bf16x8*)&Abuf[row * 32 + slot * 8];
      }
#pragma unroll
      for (int ni = 0; ni < 4; ni++){
        int row = wcol + ni * 16 + lr;
        int slot = kcr ^ ((row >> 1) & 3);
        bf[ni] = *(const bf16x8*)&Bbuf[row * 32 + slot * 8];
      }
      __builtin_amdgcn_s_setprio(1);
#pragma unroll
      for (int mi = 0; mi < 4; mi++)
#pragma unroll
        for (int ni = 0; ni < 4; ni++)
          acc[mi][ni] = __builtin_amdgcn_mfma_f32_16x16x32_bf16(af[mi], bf[ni], acc[mi][ni], 0, 0, 0);
      __builtin_amdgcn_s_setprio(0);
      asm volatile("" ::: "memory");
      __builtin_amdgcn_s_barrier();       // all waves done reading slot s
      asm volatile("" ::: "memory");
      ++s; if (s == 4) s = 0;
    }
  }
#undef STAGE
#undef SETSLICE

  // epilogue: BN affine + relu + residual
  int r0 = (l >> 4) * 4, c0 = l & 15;
#pragma unroll
  for (int ni = 0; ni < 4; ni++){
    int gcol = bBase + wcol + ni * 16 + c0;
    float sc = scale[gcol], sf = shift[gcol];
#pragma unroll
    for (int mi = 0; mi < 4; mi++){
#pragma unroll
      for (int reg = 0; reg < 4; reg++){
        int grow = aBase + wrow + mi * 16 + r0 + reg;
        size_t o = (size_t)grow * H_ + gcol;
        float val = fmaxf(acc[mi][ni][reg] * sc + sf, 0.f);
        float hv = h[o] + val;
        h[o] = hv;
        hbout[o] = f2bf(hv);
      }
    }
  }
}

extern "C" void kernel_launch(void* const* d_in, const int* in_sizes, int n_in,
                              void* d_out, int out_size, void* d_ws, size_t ws_size,
                              hipStream_t stream){
  const float* ca    = (const float*)d_in[1];
  const float* Wp    = (const float*)d_in[3];
  const float* bp    = (const float*)d_in[4];
  const float* Wlin  = (const float*)d_in[5];
  const float* blin  = (const float*)d_in[6];
  const float* Wself = (const float*)d_in[7];
  const float* bself = (const float*)d_in[8];
  const float* gam   = (const float*)d_in[9];
  const float* bet   = (const float*)d_in[10];
  const float* mean  = (const float*)d_in[11];
  const float* var   = (const float*)d_in[12];
  float* h = (float*)d_out;

  char* ws = (char*)d_ws;
  size_t off = 0;
  auto alloc = [&](size_t bytes) -> char* {
    char* p = ws + off;
    off = (off + bytes + 255) & ~(size_t)255;
    return p;
  };
  int* knn       = (int*)alloc((size_t)B_ * S_ * K_ * 4);
  int* counts    = (int*)alloc((size_t)B_ * S_ * 4);
  int* row_start = (int*)alloc((size_t)B_ * (S_ + 1) * 4);
  int* cursor    = (int*)alloc((size_t)B_ * S_ * 4);
  int* col       = (int*)alloc((size_t)B_ * S_ * K_ * 4);
  unsigned short* Wt  = (unsigned short*)alloc((size_t)L_ * H_ * KT_ * 2);
  float* scale   = (float*)alloc((size_t)L_ * H_ * 4);
  float* shift   = (float*)alloc((size_t)L_ * H_ * 4);
  unsigned short* hbA = (unsigned short*)alloc((size_t)B_ * S_ * H_ * 2);
  unsigned short* hbB = (unsigned short*)alloc((size_t)B_ * S_ * H_ * 2);
  unsigned short* hkn = (unsigned short*)alloc((size_t)B_ * S_ * H_ * 2);
  unsigned short* zbuf = (unsigned short*)alloc(4096 * 2);

  hipMemsetAsync(counts, 0, (size_t)B_ * S_ * 4, stream);
  hipMemsetAsync(zbuf, 0, 4096 * 2, stream);
  knn_kernel<<<dim3(S_ / 4, B_), 256, 0, stream>>>(ca, knn);
  count_kernel<<<dim3(B_ * S_ * K_ / 256), 256, 0, stream>>>(knn, counts);
  scan_kernel<<<dim3(B_), 256, 0, stream>>>(counts, row_start, cursor);
  fill_kernel<<<dim3(B_ * S_ * K_ / 256), 256, 0, stream>>>(knn, cursor, col);
  sort_kernel<<<dim3(B_ * S_ / 256), 256, 0, stream>>>(row_start, col);
  prepw_kernel<<<dim3((int)((size_t)L_ * H_ * KT_ / 8 / 256)), 256, 0, stream>>>(Wlin, Wself, Wt);
  prepa_kernel<<<dim3(L_ * H_ / 256), 256, 0, stream>>>(gam, bet, mean, var, blin, bself, scale, shift);
  inith_kernel<<<dim3(B_ * S_ * (H_ / 4) / 256), 256, 0, stream>>>(ca, Wp, bp, h, hbA);

  for (int l = 0; l < L_; l++){
    unsigned short* in  = (l & 1) ? hbB : hbA;
    unsigned short* out = (l & 1) ? hbA : hbB;
    hknn_kernel<<<dim3(S_, B_), 128, 0, stream>>>(in, row_start, col, hkn);
    gemmf_kernel<<<dim3((B_ * S_ / 128) * 4), 256, 0, stream>>>(
        in, hkn, Wt + (size_t)l * H_ * KT_, h, out,
        scale + l * H_, shift + l * H_, zbuf);
  }
}